// Round 3
// baseline (413.925 us; speedup 1.0000x reference)
//
#include <hip/hip_runtime.h>

// Pipeline: Conv2d(8->64,3x3,VALID)+bias -> GroupNorm(16) -> scale[c] -> MaxPool4x4 -> clip[0,1]
// x: [32,8,256,256] f32 -> out: [32,64,63,63] f32.
//
// Pass 1: tiled conv computed ONCE; per-(b,group) sum/sumsq via wave-reduce + atomics
//   into d_ws; RAW 4x4-window maxima -> d_out (GN+scale affine has A>0, so maxpool
//   commutes: max(A*y+B) = A*max(y)+B).
// Pass 2: out = clamp(A*raw + B, 0, 1), float4-vectorized, in place.
//
// R3: lane = ow mapping (stride-1 LDS reads -> conflict-free), wave = 4 oh rows
//   (one pooled row), chunk = 8 oc (acc 4x8 = 32 VGPR), weights via uniform s_load.

#define NPIX 258064.0f  // 4 * 254 * 254 elements per (b, group)

__global__ __launch_bounds__(256, 4) void conv_pool_stats(
    const float* __restrict__ x, const float* __restrict__ cw,
    const float* __restrict__ cb, float* __restrict__ pooled,
    float* __restrict__ stats)
{
    __shared__ float xs[8 * 18 * 68];   // [ic][18 rows][68-float stride] = 39168 B

    const int tid = threadIdx.x;
    const int l = tid & 63, w = tid >> 6;
    const int C0 = blockIdx.x * 64, R0 = blockIdx.y * 16;
    const int b = blockIdx.z;

    // stage x tile: 8 ic x 18 rows x 68 cols (float4 granules, zero-pad OOR)
    const float* xb = x + (size_t)b * 8 * 65536;
    for (int i = tid; i < 8 * 18 * 17; i += 256) {
        int ic = i / 306, rem = i - ic * 306;
        int r = rem / 17, g = rem - r * 17;
        int gr = R0 + r, gc = C0 + 4 * g;           // gc multiple of 4, <= 256
        float4 v = make_float4(0.f, 0.f, 0.f, 0.f);
        if (gr < 256 && gc < 256)
            v = *reinterpret_cast<const float4*>(xb + ic * 65536 + gr * 256 + gc);
        *reinterpret_cast<float4*>(xs + ic * 1224 + r * 68 + 4 * g) = v;
    }
    __syncthreads();

    const int rbase = 4 * w;                          // wave's first oh (tile-local)
    const int rv = min(4, 254 - (R0 + rbase));        // valid oh rows (2..4), wave-uniform
    const bool vow = (C0 + l) < 254;                  // lane's ow validity (stats mask)
    const int prow = blockIdx.y * 4 + w;
    const int pcol = blockIdx.x * 16 + (l >> 2);
    const bool pwr = ((l & 3) == 0) && (prow < 63) && (pcol < 63);

    #pragma unroll 1
    for (int chunk = 0; chunk < 8; ++chunk) {         // 8 oc per chunk
        const int c0 = chunk * 8;
        float acc[4][8];
        #pragma unroll
        for (int o = 0; o < 8; ++o) {
            const float bv = cb[c0 + o];              // uniform -> s_load
            acc[0][o] = bv; acc[1][o] = bv; acc[2][o] = bv; acc[3][o] = bv;
        }
        #pragma unroll 1
        for (int ic = 0; ic < 8; ++ic) {
            // weights: 8 oc x 9 taps, wave-uniform addresses -> SGPRs
            const float* wb = cw + c0 * 72 + ic * 9;
            float ws[8][9];
            #pragma unroll
            for (int o = 0; o < 8; ++o) {
                #pragma unroll
                for (int k = 0; k < 9; ++k) ws[o][k] = wb[o * 72 + k];
            }
            const float* xr = xs + ic * 1224 + rbase * 68 + l;
            #pragma unroll
            for (int r = 0; r < 6; ++r) {             // 6 input rows feed 4 oh rows
                const float x0 = xr[r * 68 + 0];
                const float x1 = xr[r * 68 + 1];
                const float x2 = xr[r * 68 + 2];
                #pragma unroll
                for (int kh = 0; kh < 3; ++kh) {
                    const int oh = r - kh;
                    if (oh < 0 || oh > 3) continue;
                    #pragma unroll
                    for (int o = 0; o < 8; ++o) {
                        acc[oh][o] = fmaf(x0, ws[o][kh * 3 + 0], acc[oh][o]);
                        acc[oh][o] = fmaf(x1, ws[o][kh * 3 + 1], acc[oh][o]);
                        acc[oh][o] = fmaf(x2, ws[o][kh * 3 + 2], acc[oh][o]);
                    }
                }
            }
        }
        // ---- epilogue: stats (masked) + pooled max ----
        float s0 = 0.f, q0 = 0.f, s1 = 0.f, q1 = 0.f;
        float pm[8];
        #pragma unroll
        for (int o = 0; o < 8; ++o) {
            float m = -3.4e38f, ss = 0.f, qq = 0.f;
            #pragma unroll
            for (int oh = 0; oh < 4; ++oh) {
                const bool vr = (oh < rv);
                const float a = acc[oh][o];
                const float av = (vr && vow) ? a : 0.0f;
                ss += av;
                qq = fmaf(av, av, qq);
                m = vr ? fmaxf(m, a) : m;
            }
            pm[o] = m;
            if (o < 4) { s0 += ss; q0 += qq; } else { s1 += ss; q1 += qq; }
        }
        #pragma unroll
        for (int o = 0; o < 8; ++o) {                 // pool across ow (4-lane groups)
            float m = pm[o];
            m = fmaxf(m, __shfl_xor(m, 1, 64));
            m = fmaxf(m, __shfl_xor(m, 2, 64));
            pm[o] = m;
        }
        if (pwr) {
            const int obase = ((b * 64 + c0) * 63 + prow) * 63 + pcol;
            #pragma unroll
            for (int o = 0; o < 8; ++o) pooled[obase + o * 3969] = pm[o];
        }
        #pragma unroll
        for (int off = 1; off < 64; off <<= 1) {
            s0 += __shfl_xor(s0, off, 64);
            q0 += __shfl_xor(q0, off, 64);
            s1 += __shfl_xor(s1, off, 64);
            q1 += __shfl_xor(q1, off, 64);
        }
        if (l == 0) {
            const int g = c0 >> 2;                    // chunk*2: two GN groups per chunk
            atomicAdd(&stats[b * 16 + g],           s0);
            atomicAdd(&stats[512 + b * 16 + g],     q0);
            atomicAdd(&stats[b * 16 + g + 1],       s1);
            atomicAdd(&stats[512 + b * 16 + g + 1], q1);
        }
    }
}

__global__ __launch_bounds__(256) void finalize_affine_clamp(
    float* __restrict__ out, const float* __restrict__ stats,
    const float* __restrict__ gnw, const float* __restrict__ gnb,
    const float* __restrict__ scale)
{
    const int i4 = blockIdx.x * 256 + threadIdx.x;
    if (i4 >= (32 * 64 * 3969) / 4) return;
    float4 v = reinterpret_cast<float4*>(out)[i4];
    float r[4] = {v.x, v.y, v.z, v.w};
    #pragma unroll
    for (int j = 0; j < 4; ++j) {
        const int i = i4 * 4 + j;
        const int bc = i / 3969;
        const int b = bc >> 6, c = bc & 63, g = c >> 2;
        const float sum = stats[b * 16 + g];
        const float ssq = stats[512 + b * 16 + g];
        const float invN = 1.0f / NPIX;
        const float mean = sum * invN;
        const float var  = ssq * invN - mean * mean;
        const float rs   = rsqrtf(var + 1e-5f);
        const float A  = rs * gnw[c] * scale[c];
        const float Bv = (gnb[c] - mean * rs * gnw[c]) * scale[c];
        float t = fmaf(A, r[j], Bv);
        r[j] = fminf(fmaxf(t, 0.0f), 1.0f);
    }
    reinterpret_cast<float4*>(out)[i4] = make_float4(r[0], r[1], r[2], r[3]);
}

extern "C" void kernel_launch(void* const* d_in, const int* in_sizes, int n_in,
                              void* d_out, int out_size, void* d_ws, size_t ws_size,
                              hipStream_t stream) {
    const float* x     = (const float*)d_in[0];
    const float* cw    = (const float*)d_in[1];
    const float* cb    = (const float*)d_in[2];
    const float* gnw   = (const float*)d_in[3];
    const float* gnb   = (const float*)d_in[4];
    const float* scale = (const float*)d_in[5];
    float* out   = (float*)d_out;
    float* stats = (float*)d_ws;

    hipMemsetAsync(d_ws, 0, 1024 * sizeof(float), stream);

    dim3 grid1(4, 16, 32);
    conv_pool_stats<<<grid1, 256, 0, stream>>>(x, cw, cb, out, stats);

    const int total4 = (32 * 64 * 3969) / 4;
    finalize_affine_clamp<<<(total4 + 255) / 256, 256, 0, stream>>>(out, stats, gnw, gnb, scale);
}